// Round 7
// baseline (102.438 us; speedup 1.0000x reference)
//
#include <hip/hip_runtime.h>
#include <hip/hip_bf16.h>

// TripletBatchHardLoss: N=8192, D=256, fp32 embeddings (L2-normalized), int32 labels.
// Normalized -> pdist monotone DECREASING in dot:
//   hard_negative = max dot over negs, hard_positive = min dot over poss (diag dot~1 safe).
// R22 = OCCUPANCY PUSH: R15's proven 2-barrier dbuf K-step, re-tiled 128x64 per block
// (wave-tile 64x32, acc[4][2]=32 AGPR) so unified VGPR ~96 fits launch_bounds(256,4):
// 4 blocks/CU = 16 waves/CU (+33% TLP over R15's 12).
//   - R15-R21 post-mortem: three sync structures (1-barrier 3-buf, 0-barrier independent,
//     persistent chunks) all land 42-45us tile; no pipe >30%; occupancy measured 17-27%
//     in every round. DMA service rate and staging BW ruled out via R20's counters
//     (58 cyc/DMA, 4x bytes, same time). Remaining theory: un-hidden latency, too few
//     waves. The never-tried axis is shrinking acc to buy waves/CU.
//   - 4160 tiles: J in [0,128) over 64-col groups, I in [0, J/2] over 128-row groups
//     (J>=2I covers all unordered pairs; diagonal-band duplicates idempotent).
//     cum(2u)=u(u+1), cum(2u+1)=(u+1)^2 -> closed-form decode + fixup.
//   - 4160 % 8 == 0 -> free bijective XCD swizzle (t = (b&7)*520 + (b>>3)): consecutive
//     t per XCD share J (B-panel) -> same-XCD L2 reuse on staging reads.
//   - 3 DMAs/wave/step (A:2, B:1) -> counted vmcnt(3) mid-loop, vmcnt(0) only at kt7.
//   - LDS 16(A)+8(B)+3(red) = 27KB; epilogue scratch overlays sA[0] (last sA[0] reads
//     are kt6, fenced by kt6's trailing barrier; kt7 reads buf1 only).
// VGPR discipline: acc 32 + af 16 + bf 8 + epilogue live ~96 <= 128 cap of (256,4).
// No __threadfence in wide kernels (R11: per-block fence = per-XCD L2 writeback, +130 us).

#define NS 8192
#define DD 256
#define NT 4160
#define EPS_PD 1e-12f
#define BIGF 1e30f

typedef unsigned short u16;
typedef unsigned int u32;
typedef short short8 __attribute__((ext_vector_type(8)));
typedef float f32x4 __attribute__((ext_vector_type(4)));

typedef const __attribute__((address_space(1))) u32 glb_u32;
typedef __attribute__((address_space(3))) u32 lds_u32;

__device__ __forceinline__ void async16(const void* g, void* l) {
    __builtin_amdgcn_global_load_lds((glb_u32*)g, (lds_u32*)l, 16, 0, 0);
}

// order-preserving float <-> uint key (unsigned compare == float compare)
__device__ __forceinline__ u32 fkey(float f) {
    u32 b = __float_as_uint(f);
    return (b & 0x80000000u) ? ~b : (b | 0x80000000u);
}
__device__ __forceinline__ float unkey(u32 k) {
    u32 b = (k & 0x80000000u) ? (k ^ 0x80000000u) : ~k;
    return __uint_as_float(b);
}

__device__ __forceinline__ u16 f2bf_rne(float f) {
    u32 b = __float_as_uint(f);
    b += 0x7FFFu + ((b >> 16) & 1u);
    return (u16)(b >> 16);
}

// DPP lane-move within 16-lane rows (reduction groups are exactly DPP rows)
template <int CTRL>
__device__ __forceinline__ float dpp_mov(float x) {
    return __int_as_float(
        __builtin_amdgcn_update_dpp(0, __float_as_int(x), CTRL, 0xF, 0xF, true));
}

// cumulative tile count below column-group J: cum(2u)=u(u+1), cum(2u+1)=(u+1)^2
__device__ __forceinline__ int cumJ(int J) {
    const int u = J >> 1;
    return (J & 1) ? (u + 1) * (u + 1) : u * (u + 1);
}

// ---------------- kernel 1: fp32 -> bf16, row sum-of-squares, init keys ----------------
__global__ __launch_bounds__(256) void prep_kernel(
    const float* __restrict__ e, u16* __restrict__ ebf, float* __restrict__ sq,
    u32* __restrict__ mxk, u32* __restrict__ mnk, float* __restrict__ out) {
    const int tid = blockIdx.x * 256 + threadIdx.x;   // 2048 blocks
    const int row = tid >> 6, t = tid & 63;           // one wave per row
    float4 v = ((const float4*)(e + (size_t)row * DD))[t];
    ushort4 u;
    u.x = f2bf_rne(v.x); u.y = f2bf_rne(v.y); u.z = f2bf_rne(v.z); u.w = f2bf_rne(v.w);
    ((ushort4*)(ebf + (size_t)row * DD))[t] = u;
    float s = v.x * v.x + v.y * v.y + v.z * v.z + v.w * v.w;
    for (int o = 32; o; o >>= 1) s += __shfl_down(s, o);
    if (t == 0) {
        sq[row] = s;
        mxk[row] = 0u;            // sentinel for unsigned max
        mnk[row] = 0xFFFFFFFFu;   // sentinel for unsigned min
        if (row == 0) out[0] = 0.0f;
    }
}

// ------- kernel 2: dbuf 128x64 triangular dot-GEMM + two-sided masked reduction --------
__global__ __launch_bounds__(256, 4) void tile_kernel(
    const u16* __restrict__ ebf, const int* __restrict__ labels,
    u32* __restrict__ mxk, u32* __restrict__ mnk) {
    // A: 128x32 (512 16B-slots), B: 64x32 (256 slots); slot (row,c) at row*4 + (c^((row>>2)&3))
    __shared__ __attribute__((aligned(16))) u16 sA[2][4096];   // 2 x 8 KB
    __shared__ __attribute__((aligned(16))) u16 sB[2][2048];   // 2 x 4 KB

    // XCD-bijective swizzle (4160 = 8*520): consecutive t per XCD share J / B-panel
    const int b = blockIdx.x;
    const int t = (b & 7) * 520 + (b >> 3);

    // decode t -> (J, I): J in [0,128), I in [0, (J>>1)]
    int j = (int)(2.0f * sqrtf((float)t + 1.0f));
    if (j > 127) j = 127;
    while (cumJ(j) > t) --j;
    while (cumJ(j + 1) <= t) ++j;
    const int I = t - cumJ(j);
    const int bi = I * 128, bj = j * 64;

    const int tid = threadIdx.x;
    const int lane = tid & 63, wid = tid >> 6;
    const int wm = wid >> 1, wn = wid & 1;            // wave tile: rows wm*64+, cols wn*32+
    const int l15 = lane & 15, q = lane >> 4;

    // staging: A slots [wid*128, +128) (2 DMAs/wave); B slots [wid*64, +64) (1 DMA/wave)
    const int sa0 = wid * 128 + lane, sa1 = sa0 + 64;
    const int ra0 = sa0 >> 2, ca0 = (sa0 & 3) ^ ((ra0 >> 2) & 3);
    const int ra1 = sa1 >> 2, ca1 = (sa1 & 3) ^ ((ra1 >> 2) & 3);
    const int sb0 = wid * 64 + lane;
    const int rb0 = sb0 >> 2, cb0 = (sb0 & 3) ^ ((rb0 >> 2) & 3);
    const u16* gA0 = ebf + (size_t)(bi + ra0) * DD + ca0 * 8;
    const u16* gA1 = ebf + (size_t)(bi + ra1) * DD + ca1 * 8;
    const u16* gB0 = ebf + (size_t)(bj + rb0) * DD + cb0 * 8;
    const int adst0 = wid * 1024, adst1 = adst0 + 512;   // u16 offsets
    const int bdst0 = wid * 512;

    // frag-read offsets (u16): row stride 32; chunk q -> slot row*4 + (q^((row>>2)&3)).
    // A rows wm*64+mi*16+l15, B rows wn*32+ni*16+l15: wm*16/mi*4/wn*8/ni*4 all == 0 mod 4
    // in (row>>2)&3, so swz depends on l15,q only.
    const int swz = (q ^ (l15 >> 2)) * 8;
    const int offa = (wm * 64 + l15) * 32 + swz;   // + mi*512
    const int offb = (wn * 32 + l15) * 32 + swz;   // + ni*512

#define ISSUE_TILE(buf, ko)                                   \
    do {                                                      \
        async16(gA0 + (ko), &sA[buf][adst0]);                 \
        async16(gA1 + (ko), &sA[buf][adst1]);                 \
        async16(gB0 + (ko), &sB[buf][bdst0]);                 \
    } while (0)

    // prologue: K-step 0 into buffer 0 (3 DMAs per wave)
    ISSUE_TILE(0, 0);

    f32x4 acc[4][2] = {};
#pragma unroll
    for (int kt = 0; kt < 8; ++kt) {
        const int cur = kt & 1, nxt = cur ^ 1;
        if (kt < 7) {   // prefetch kt+1 (issued BEFORE the wait), then drain kt's 3
            ISSUE_TILE(nxt, (kt + 1) * 32);
            asm volatile("s_waitcnt vmcnt(3)\n\ts_barrier" ::: "memory");
        } else {
            asm volatile("s_waitcnt vmcnt(0)\n\ts_barrier" ::: "memory");
        }
        short8 af[4], bfr[2];
#pragma unroll
        for (int mi = 0; mi < 4; ++mi)
            af[mi] = *(const short8*)(&sA[cur][offa + mi * 512]);
#pragma unroll
        for (int ni = 0; ni < 2; ++ni)
            bfr[ni] = *(const short8*)(&sB[cur][offb + ni * 512]);
#pragma unroll
        for (int mi = 0; mi < 4; ++mi)
#pragma unroll
            for (int ni = 0; ni < 2; ++ni)
                acc[mi][ni] = __builtin_amdgcn_mfma_f32_16x16x32_bf16(
                    af[mi], bfr[ni], acc[mi][ni], 0, 0, 0);
        if (kt < 7) {
            // WAR guard: all waves done reading buf[cur] before body kt+1's DMA clobbers it
            asm volatile("s_waitcnt lgkmcnt(0)\n\ts_barrier" ::: "memory");
        }
    }

    // ---- epilogue: C/D layout col = lane&15, row = q*4 + reg (m89-verified) ----
    // output rows bi + wm*64 + mi*16 + q*4 + r2; cols bj + wn*32 + ni*16 + l15
    int li[4][4];
#pragma unroll
    for (int mi = 0; mi < 4; ++mi) {
        const int4 v = *(const int4*)(labels + bi + wm * 64 + mi * 16 + q * 4);
        li[mi][0] = v.x; li[mi][1] = v.y; li[mi][2] = v.z; li[mi][3] = v.w;
    }
    int lj[2];
#pragma unroll
    for (int ni = 0; ni < 2; ++ni) lj[ni] = labels[bj + wn * 32 + ni * 16 + l15];

    float mxn[4][4], mnp[4][4];                        // row-side per (mi, r)
    float mxc[2] = {-BIGF, -BIGF};                     // col-side per ni
    float mnc[2] = {BIGF, BIGF};
#pragma unroll
    for (int mi = 0; mi < 4; ++mi)
#pragma unroll
        for (int r2 = 0; r2 < 4; ++r2) { mxn[mi][r2] = -BIGF; mnp[mi][r2] = BIGF; }

#pragma unroll
    for (int mi = 0; mi < 4; ++mi)
#pragma unroll
        for (int ni = 0; ni < 2; ++ni) {
            const int l = lj[ni];
#pragma unroll
            for (int r2 = 0; r2 < 4; ++r2) {
                const float d = acc[mi][ni][r2];
                const bool same = (li[mi][r2] == l);
                const float sneg = same ? -BIGF : d;
                const float spos = same ? d : BIGF;
                mxn[mi][r2] = fmaxf(mxn[mi][r2], sneg);
                mnp[mi][r2] = fminf(mnp[mi][r2], spos);
                mxc[ni] = fmaxf(mxc[ni], sneg);
                mnc[ni] = fminf(mnc[ni], spos);
            }
        }

    // col-side: reduce over q (lanes l15, +16, +32, +48) via shfl_xor 16/32
#pragma unroll
    for (int ni = 0; ni < 2; ++ni) {
        mxc[ni] = fmaxf(mxc[ni], __shfl_xor(mxc[ni], 16));
        mnc[ni] = fminf(mnc[ni], __shfl_xor(mnc[ni], 16));
        mxc[ni] = fmaxf(mxc[ni], __shfl_xor(mxc[ni], 32));
        mnc[ni] = fminf(mnc[ni], __shfl_xor(mnc[ni], 32));
    }
    // row-side: 16-lane DPP reduction (xor1, xor2, ror4, ror8)
#pragma unroll
    for (int mi = 0; mi < 4; ++mi)
#pragma unroll
        for (int r2 = 0; r2 < 4; ++r2) {
            float x = mxn[mi][r2], n = mnp[mi][r2];
            x = fmaxf(x, dpp_mov<0xB1>(x));  n = fminf(n, dpp_mov<0xB1>(n));
            x = fmaxf(x, dpp_mov<0x4E>(x));  n = fminf(n, dpp_mov<0x4E>(n));
            x = fmaxf(x, dpp_mov<0x124>(x)); n = fminf(n, dpp_mov<0x124>(n));
            x = fmaxf(x, dpp_mov<0x128>(x)); n = fminf(n, dpp_mov<0x128>(n));
            mxn[mi][r2] = x; mnp[mi][r2] = n;
        }

    // ---- block-level LDS combine -> 6 atomic wave-instrs total ----
    // scratch overlays sA[0] (last sA[0] reads were kt6, fenced by kt6's trailing
    // barrier; kt7 reads buf1 only). Layout (floats): [0..255] rowmax[row][wn],
    // [256..511] rowmin, [512..639] colmax[col][wm], [640..767] colmin. 3 KB.
    float* red = (float*)&sA[0][0];
    if (l15 == 0) {
#pragma unroll
        for (int mi = 0; mi < 4; ++mi)
#pragma unroll
            for (int r2 = 0; r2 < 4; ++r2) {
                const int rl = wm * 64 + mi * 16 + q * 4 + r2;
                red[rl * 2 + wn] = mxn[mi][r2];
                red[256 + rl * 2 + wn] = mnp[mi][r2];
            }
    }
    if (q == 0) {
#pragma unroll
        for (int ni = 0; ni < 2; ++ni) {
            const int cl = wn * 32 + ni * 16 + l15;
            red[512 + cl * 2 + wm] = mxc[ni];
            red[640 + cl * 2 + wm] = mnc[ni];
        }
    }
    __syncthreads();
    if (tid < 128) {
        const float mx = fmaxf(red[tid * 2], red[tid * 2 + 1]);
        const float mn = fminf(red[256 + tid * 2], red[256 + tid * 2 + 1]);
        atomicMax(&mxk[bi + tid], fkey(mx));
        atomicMin(&mnk[bi + tid], fkey(mn));
    } else if (tid < 192) {
        const int c = tid - 128;
        const float mx = fmaxf(red[512 + c * 2], red[512 + c * 2 + 1]);
        const float mn = fminf(red[640 + c * 2], red[640 + c * 2 + 1]);
        atomicMax(&mxk[bj + c], fkey(mx));
        atomicMin(&mnk[bj + c], fkey(mn));
    }
}

// ---------------- kernel 3: per-row loss + mean ----------------
__global__ __launch_bounds__(256) void finalize_kernel(
    const u32* __restrict__ mxk, const u32* __restrict__ mnk,
    const float* __restrict__ sq, float* __restrict__ out) {
    const int i = blockIdx.x * 256 + threadIdx.x;
    const float s = sq[i] + 1.0f;   // sq_i + sq_j, sq_j = 1 +- 1e-7
    const float hn = sqrtf(fmaxf(fmaf(-2.0f, unkey(mxk[i]), s), EPS_PD));
    const float hp = sqrtf(fmaxf(fmaf(-2.0f, unkey(mnk[i]), s), EPS_PD));
    float loss = fmaxf(hp - hn + 1.0f, 0.0f);
    for (int o = 32; o; o >>= 1) loss += __shfl_down(loss, o);
    __shared__ float wsum[4];
    const int lane = threadIdx.x & 63, w = threadIdx.x >> 6;
    if (lane == 0) wsum[w] = loss;
    __syncthreads();
    if (threadIdx.x == 0)
        atomicAdd(out, (wsum[0] + wsum[1] + wsum[2] + wsum[3]) * (1.0f / NS));
}

extern "C" void kernel_launch(void* const* d_in, const int* in_sizes, int n_in,
                              void* d_out, int out_size, void* d_ws, size_t ws_size,
                              hipStream_t stream) {
    const int* labels = (const int*)d_in[0];
    const float* emb = (const float*)d_in[1];
    float* out = (float*)d_out;

    char* ws = (char*)d_ws;
    u16* ebf = (u16*)ws;                                     // 4 MB
    float* sq = (float*)(ws + (size_t)NS * DD * 2);          // 32 KB
    u32* mxk = (u32*)(ws + (size_t)NS * DD * 2 + NS * 4);
    u32* mnk = mxk + NS;

    prep_kernel<<<NS * DD / 4 / 256, 256, 0, stream>>>(emb, ebf, sq, mxk, mnk, out);
    tile_kernel<<<NT, 256, 0, stream>>>(ebf, labels, mxk, mnk);
    finalize_kernel<<<NS / 256, 256, 0, stream>>>(mxk, mnk, sq, out);
}